// Round 1
// baseline (585.869 us; speedup 1.0000x reference)
//
#include <hip/hip_runtime.h>

// ---------- types ----------
typedef __attribute__((ext_vector_type(8))) short short8;
typedef __attribute__((ext_vector_type(8))) unsigned short ushort8;
typedef __attribute__((ext_vector_type(4))) float f32x4;

__device__ __forceinline__ float b2f(short s) {
    unsigned u = ((unsigned)(unsigned short)s) << 16;
    return __builtin_bit_cast(float, u);
}
__device__ __forceinline__ unsigned short f2b(float f) {
    unsigned u = __builtin_bit_cast(unsigned, f);
    u += 0x7fffu + ((u >> 16) & 1u);   // round-to-nearest-even
    return (unsigned short)(u >> 16);
}

// global -> LDS async copy, 16B per lane (wave-uniform LDS base + lane*16)
__device__ __forceinline__ void gload_lds16(const void* gptr, void* ldsptr) {
    typedef __attribute__((address_space(1))) const void gv_t;
    typedef __attribute__((address_space(3))) void lv_t;
    gv_t* g = reinterpret_cast<gv_t*>(reinterpret_cast<unsigned long long>(gptr));
    lv_t* l = reinterpret_cast<lv_t*>((unsigned int)reinterpret_cast<unsigned long long>(ldsptr));
    __builtin_amdgcn_global_load_lds(g, l, 16, 0, 0);
}

// ---------- fp32 -> bf16 conversion (8 elems/thread) ----------
__global__ __launch_bounds__(256) void cvt_bf16(const float* __restrict__ in,
                                                unsigned short* __restrict__ out,
                                                int n8) {
    int i = blockIdx.x * 256 + threadIdx.x;
    if (i >= n8) return;
    const float4* p = (const float4*)in + (size_t)i * 2;
    float4 a = p[0], b = p[1];
    ushort8 o;
    o[0] = f2b(a.x); o[1] = f2b(a.y); o[2] = f2b(a.z); o[3] = f2b(a.w);
    o[4] = f2b(b.x); o[5] = f2b(b.y); o[6] = f2b(b.z); o[7] = f2b(b.w);
    *(ushort8*)(out + (size_t)i * 8) = o;
}

// ---------- concat 3 bias vectors (each 1024) ----------
__global__ __launch_bounds__(256) void concat3(const float* __restrict__ a,
                                               const float* __restrict__ b,
                                               const float* __restrict__ c,
                                               float* __restrict__ o) {
    int i = blockIdx.x * 256 + threadIdx.x;  // 0..3071
    float v = (i < 1024) ? a[i] : (i < 2048 ? b[i - 1024] : c[i - 2048]);
    o[i] = v;
}

// ---------- bf16 GEMM, C[m,n] = sum_k A[m,k]*B[n,k] + bias[n] ----------
// m97 structure: 128x128 tile, BK=64, 4 waves (2x2), 16x16x32 MFMA,
// global_load_lds width-16 staging, single-buffered LDS.
template <bool OUT_BF16>
__global__ __launch_bounds__(256) void gemm_bt(const short* __restrict__ A,   // [M,K] bf16
                                               const short* __restrict__ B,   // [N,K] bf16
                                               const float* __restrict__ bias,// [N]
                                               unsigned short* __restrict__ Cb,
                                               float* __restrict__ Cf,
                                               int M, int N, int K) {
    __shared__ short As[128][64];
    __shared__ short Bs[128][64];

    const int lane = threadIdx.x & 63;
    const int wave = threadIdx.x >> 6;
    const int wr = wave >> 1, wc = wave & 1;

    f32x4 acc[4][4] = {};

    // staging source: lane l of wave w loads row (w*8 + l/8), col (l%8)*8 of the tile
    const int srow = wave * 8 + (lane >> 3);
    const int scol = (lane & 7) * 8;
    const short* Abase = A + (size_t)(blockIdx.y * 128 + srow) * K + scol;
    const short* Bbase = B + (size_t)(blockIdx.x * 128 + srow) * K + scol;
    short* AsBase = &As[wave * 8][0];
    short* BsBase = &Bs[wave * 8][0];

    for (int kt = 0; kt < K; kt += 64) {
#pragma unroll
        for (int i = 0; i < 4; ++i) {
            gload_lds16(Abase + kt + (size_t)i * 32 * K, AsBase + i * 32 * 64);
            gload_lds16(Bbase + kt + (size_t)i * 32 * K, BsBase + i * 32 * 64);
        }
        __syncthreads();
#pragma unroll
        for (int ks = 0; ks < 2; ++ks) {
            short8 af[4], bfr[4];
#pragma unroll
            for (int m = 0; m < 4; ++m)
                af[m] = *(const short8*)&As[wr * 64 + m * 16 + (lane & 15)][ks * 32 + (lane >> 4) * 8];
#pragma unroll
            for (int n = 0; n < 4; ++n)
                bfr[n] = *(const short8*)&Bs[wc * 64 + n * 16 + (lane & 15)][ks * 32 + (lane >> 4) * 8];
#pragma unroll
            for (int m = 0; m < 4; ++m)
#pragma unroll
                for (int n = 0; n < 4; ++n)
                    acc[m][n] = __builtin_amdgcn_mfma_f32_16x16x32_bf16(af[m], bfr[n], acc[m][n], 0, 0, 0);
        }
        __syncthreads();
    }

    // epilogue: C/D layout col = lane&15, row = (lane>>4)*4 + r
    const int crow0 = blockIdx.y * 128 + wr * 64 + (lane >> 4) * 4;
    const int ccol0 = blockIdx.x * 128 + wc * 64 + (lane & 15);
#pragma unroll
    for (int n = 0; n < 4; ++n) {
        int col = ccol0 + n * 16;
        float bv = bias[col];
#pragma unroll
        for (int m = 0; m < 4; ++m) {
            int row0 = crow0 + m * 16;
#pragma unroll
            for (int r = 0; r < 4; ++r) {
                float val = acc[m][n][r] + bv;
                if (OUT_BF16) Cb[(size_t)(row0 + r) * N + col] = f2b(val);
                else          Cf[(size_t)(row0 + r) * N + col] = val;
            }
        }
    }
}

// ---------- per-token cross-head attention ----------
// qkv: [N, 3072] bf16 (q | k | v), out: [N, 1024] bf16
// one thread per (token, head): 16x16 scores, softmax over key-heads, 16x64 PV
__global__ __launch_bounds__(256) void attn_k(const short* __restrict__ qkv,
                                              short* __restrict__ out) {
    int gid = blockIdx.x * 256 + threadIdx.x;
    int t = gid >> 4, h = gid & 15;
    const short* q  = qkv + (size_t)t * 3072 + h * 64;
    const short* kb = qkv + (size_t)t * 3072 + 1024;
    const short* vb = qkv + (size_t)t * 3072 + 2048;

    float qf[64];
#pragma unroll
    for (int j = 0; j < 8; ++j) {
        short8 qv = *(const short8*)(q + j * 8);
#pragma unroll
        for (int i = 0; i < 8; ++i) qf[j * 8 + i] = b2f(qv[i]);
    }

    float s[16];
    float mx = -1e30f;
#pragma unroll
    for (int g = 0; g < 16; ++g) {
        float a = 0.f;
#pragma unroll
        for (int j = 0; j < 8; ++j) {
            short8 kv = *(const short8*)(kb + g * 64 + j * 8);
#pragma unroll
            for (int i = 0; i < 8; ++i) a += qf[j * 8 + i] * b2f(kv[i]);
        }
        s[g] = a * 0.125f;   // scale = 1/sqrt(64)
        mx = fmaxf(mx, s[g]);
    }
    float den = 0.f;
#pragma unroll
    for (int g = 0; g < 16; ++g) { s[g] = __expf(s[g] - mx); den += s[g]; }
    float inv = 1.f / den;

#pragma unroll
    for (int j = 0; j < 8; ++j) {
        float o[8] = {0.f, 0.f, 0.f, 0.f, 0.f, 0.f, 0.f, 0.f};
#pragma unroll
        for (int g = 0; g < 16; ++g) {
            short8 vv = *(const short8*)(vb + g * 64 + j * 8);
            float w = s[g];
#pragma unroll
            for (int i = 0; i < 8; ++i) o[i] += w * b2f(vv[i]);
        }
        short8 ov;
#pragma unroll
        for (int i = 0; i < 8; ++i) ov[i] = (short)f2b(o[i] * inv);
        *(short8*)(out + (size_t)t * 1024 + h * 64 + j * 8) = ov;
    }
}

// ---------- launch ----------
extern "C" void kernel_launch(void* const* d_in, const int* in_sizes, int n_in,
                              void* d_out, int out_size, void* d_ws, size_t ws_size,
                              hipStream_t stream) {
    const float* x  = (const float*)d_in[0];
    const float* Wq = (const float*)d_in[1];
    const float* bq = (const float*)d_in[2];
    const float* Wk = (const float*)d_in[3];
    const float* bk = (const float*)d_in[4];
    const float* Wv = (const float*)d_in[5];
    const float* bv = (const float*)d_in[6];
    const float* Wo = (const float*)d_in[7];
    const float* bo = (const float*)d_in[8];
    float* out = (float*)d_out;

    const int N = 32768, E = 1024;

    char* ws = (char*)d_ws;
    size_t off = 0;
    short* xb = (short*)(ws + off);         off += (size_t)N * E * 2;          // 64 MiB
    short* wqkv = (short*)(ws + off);       off += (size_t)3 * E * E * 2;      // 6 MiB
    short* wo = (short*)(ws + off);         off += (size_t)E * E * 2;          // 2 MiB
    float* bqkv = (float*)(ws + off);       off += (size_t)3 * E * 4;          // 12 KiB
    short* y1 = (short*)(ws + off);         off += (size_t)N * 3 * E * 2;      // 192 MiB
    short* ao = xb;  // reuse xb region: dead after GEMM1, attn writes here

    // 1) convert x and weights to bf16
    cvt_bf16<<<dim3((N * E / 8 + 255) / 256), dim3(256), 0, stream>>>(x, (unsigned short*)xb, N * E / 8);
    cvt_bf16<<<dim3((E * E / 8 + 255) / 256), dim3(256), 0, stream>>>(Wq, (unsigned short*)wqkv, E * E / 8);
    cvt_bf16<<<dim3((E * E / 8 + 255) / 256), dim3(256), 0, stream>>>(Wk, (unsigned short*)(wqkv + (size_t)E * E), E * E / 8);
    cvt_bf16<<<dim3((E * E / 8 + 255) / 256), dim3(256), 0, stream>>>(Wv, (unsigned short*)(wqkv + (size_t)2 * E * E), E * E / 8);
    cvt_bf16<<<dim3((E * E / 8 + 255) / 256), dim3(256), 0, stream>>>(Wo, (unsigned short*)wo, E * E / 8);
    concat3<<<dim3(12), dim3(256), 0, stream>>>(bq, bk, bv, bqkv);

    // 2) fused QKV projection: y1[N, 3072] = xb @ wqkv^T + bqkv  (bf16 out)
    gemm_bt<true><<<dim3(3 * E / 128, N / 128), dim3(256), 0, stream>>>(
        xb, wqkv, bqkv, (unsigned short*)y1, nullptr, N, 3 * E, E);

    // 3) per-token attention: ao[N, 1024] bf16
    attn_k<<<dim3(N * 16 / 256), dim3(256), 0, stream>>>(y1, ao);

    // 4) output projection: out[N, 1024] = ao @ wo^T + bo  (fp32 out)
    gemm_bt<false><<<dim3(E / 128, N / 128), dim3(256), 0, stream>>>(
        ao, wo, bo, nullptr, out, N, E, E);
}

// Round 2
// 503.136 us; speedup vs baseline: 1.1644x; 1.1644x over previous
//
#include <hip/hip_runtime.h>

// ---------- types ----------
typedef __attribute__((ext_vector_type(8))) short short8;
typedef __attribute__((ext_vector_type(8))) unsigned short ushort8;
typedef __attribute__((ext_vector_type(4))) float f32x4;

__device__ __forceinline__ float b2f(short s) {
    unsigned u = ((unsigned)(unsigned short)s) << 16;
    return __builtin_bit_cast(float, u);
}
__device__ __forceinline__ unsigned short f2b(float f) {
    unsigned u = __builtin_bit_cast(unsigned, f);
    u += 0x7fffu + ((u >> 16) & 1u);   // round-to-nearest-even
    return (unsigned short)(u >> 16);
}

// global -> LDS async copy, 16B per lane (wave-uniform LDS base + lane*16)
__device__ __forceinline__ void gload_lds16(const void* gptr, void* ldsptr) {
    typedef __attribute__((address_space(1))) const void gv_t;
    typedef __attribute__((address_space(3))) void lv_t;
    gv_t* g = reinterpret_cast<gv_t*>(reinterpret_cast<unsigned long long>(gptr));
    lv_t* l = reinterpret_cast<lv_t*>((unsigned int)reinterpret_cast<unsigned long long>(ldsptr));
    __builtin_amdgcn_global_load_lds(g, l, 16, 0, 0);
}

#define MEMFENCE() asm volatile("" ::: "memory")
#define BARRIER() do { MEMFENCE(); __builtin_amdgcn_s_barrier(); MEMFENCE(); } while (0)

// ---------- fp32 -> bf16 conversion (8 elems/thread) ----------
__global__ __launch_bounds__(256) void cvt_bf16(const float* __restrict__ in,
                                                unsigned short* __restrict__ out,
                                                int n8) {
    int i = blockIdx.x * 256 + threadIdx.x;
    if (i >= n8) return;
    const float4* p = (const float4*)in + (size_t)i * 2;
    float4 a = p[0], b = p[1];
    ushort8 o;
    o[0] = f2b(a.x); o[1] = f2b(a.y); o[2] = f2b(a.z); o[3] = f2b(a.w);
    o[4] = f2b(b.x); o[5] = f2b(b.y); o[6] = f2b(b.z); o[7] = f2b(b.w);
    *(ushort8*)(out + (size_t)i * 8) = o;
}

// ---------- concat 3 bias vectors (each 1024) ----------
__global__ __launch_bounds__(256) void concat3(const float* __restrict__ a,
                                               const float* __restrict__ b,
                                               const float* __restrict__ c,
                                               float* __restrict__ o) {
    int i = blockIdx.x * 256 + threadIdx.x;  // 0..3071
    float v = (i < 1024) ? a[i] : (i < 2048 ? b[i - 1024] : c[i - 2048]);
    o[i] = v;
}

// ---------- bf16 GEMM, C[m,n] = sum_k A[m,k]*B[n,k] + bias[n] ----------
// BM=256, BN=128, BK=64, 512 threads (8 waves, 4x2), 16x16x32 MFMA.
// 3-deep LDS pipeline with counted vmcnt (T4): stage tile t+2 while computing t,
// wait vmcnt(12) (= 2 tiles x 6 loads in flight), never drain to 0 in the loop.
// LDS XOR-swizzle (T2, both sides): global source pre-swizzled per-lane
// (granule ^= row&7) since global_load_lds writes linearly; ds_read applies
// the same XOR. XCD-aware block swizzle (T1); nwg % 8 == 0 for both calls.
template <bool OUT_BF16>
__global__ __launch_bounds__(512, 2) void gemm_bt(const short* __restrict__ A,   // [M,K] bf16
                                                  const short* __restrict__ B,   // [N,K] bf16
                                                  const float* __restrict__ bias,// [N]
                                                  unsigned short* __restrict__ Cb,
                                                  float* __restrict__ Cf,
                                                  int M, int N, int K) {
    __shared__ short As[3][256][64];   // 96 KiB
    __shared__ short Bs[3][128][64];   // 48 KiB

    const int lane = threadIdx.x & 63;
    const int wave = threadIdx.x >> 6;
    const int wr = wave >> 1;          // 0..3: wave row (64 rows each)
    const int wc = wave & 1;           // 0..1: wave col (64 cols each)

    // XCD-aware swizzle: each XCD gets a contiguous chunk of tiles
    const int nwg = gridDim.x;
    const int bid = blockIdx.x;
    const int swz = (bid & 7) * (nwg >> 3) + (bid >> 3);
    const int ncol = N >> 7;
    const int trow = swz / ncol, tcol = swz % ncol;

    const short* Ablk = A + (size_t)trow * 256 * K;
    const short* Bblk = B + (size_t)tcol * 128 * K;

    // staging addressing: per gload, wave covers an 8-row stripe (1024 B);
    // lane l writes phys granule l&7 of row stripe*8+(l>>3); the global
    // source column is pre-swizzled so LDS-phys holds swizzled content.
    const int srow_off = lane >> 3;                 // 0..7 within stripe
    const int scol_sw = ((lane & 7) ^ (lane >> 3)) * 8;  // shorts

    f32x4 acc[4][4] = {};

    const int NT = K >> 6;

    auto stage = [&](int t, int b) {
        const int kt = t << 6;  // short offset along K
#pragma unroll
        for (int i = 0; i < 4; ++i) {               // A: 32 stripes / 8 waves
            int stripe = i * 8 + wave;
            const short* src = Ablk + (size_t)(stripe * 8 + srow_off) * K + kt + scol_sw;
            gload_lds16(src, &As[b][stripe * 8][0]);
        }
#pragma unroll
        for (int i = 0; i < 2; ++i) {               // B: 16 stripes / 8 waves
            int stripe = i * 8 + wave;
            const short* src = Bblk + (size_t)(stripe * 8 + srow_off) * K + kt + scol_sw;
            gload_lds16(src, &Bs[b][stripe * 8][0]);
        }
    };

    auto compute = [&](int b) {
        short8 af[4][2], bf[4][2];
#pragma unroll
        for (int m = 0; m < 4; ++m) {
            int lr = wr * 64 + m * 16 + (lane & 15);
#pragma unroll
            for (int ks = 0; ks < 2; ++ks) {
                int g = (ks * 4 + (lane >> 4)) ^ (lane & 7);   // lr&7 == lane&7
                af[m][ks] = *(const short8*)&As[b][lr][g * 8];
            }
        }
#pragma unroll
        for (int n = 0; n < 4; ++n) {
            int br = wc * 64 + n * 16 + (lane & 15);
#pragma unroll
            for (int ks = 0; ks < 2; ++ks) {
                int g = (ks * 4 + (lane >> 4)) ^ (lane & 7);
                bf[n][ks] = *(const short8*)&Bs[b][br][g * 8];
            }
        }
#pragma unroll
        for (int ks = 0; ks < 2; ++ks)
#pragma unroll
            for (int m = 0; m < 4; ++m)
#pragma unroll
                for (int n = 0; n < 4; ++n)
                    acc[m][n] = __builtin_amdgcn_mfma_f32_16x16x32_bf16(af[m][ks], bf[n][ks], acc[m][n], 0, 0, 0);
    };

    // prologue: 2 tiles in flight
    stage(0, 0);
    stage(1, 1);

    for (int t = 0; t < NT; ++t) {
        if (t + 2 < NT) {
            stage(t + 2, (t + 2) % 3);
            asm volatile("s_waitcnt vmcnt(12)" ::: "memory");  // tile t landed
        } else if (t + 1 < NT) {
            asm volatile("s_waitcnt vmcnt(6)" ::: "memory");
        } else {
            asm volatile("s_waitcnt vmcnt(0)" ::: "memory");
        }
        BARRIER();              // all waves' tile-t stages visible
        compute(t % 3);
        BARRIER();              // reads of buf t%3 done before it's re-staged
    }

    // epilogue: C/D layout col = lane&15, row = (lane>>4)*4 + r
    const int crow0 = trow * 256 + wr * 64 + (lane >> 4) * 4;
    const int ccol0 = tcol * 128 + wc * 64 + (lane & 15);
#pragma unroll
    for (int n = 0; n < 4; ++n) {
        int col = ccol0 + n * 16;
        float bv = bias[col];
#pragma unroll
        for (int m = 0; m < 4; ++m) {
            int row0 = crow0 + m * 16;
#pragma unroll
            for (int r = 0; r < 4; ++r) {
                float val = acc[m][n][r] + bv;
                if (OUT_BF16) Cb[(size_t)(row0 + r) * N + col] = f2b(val);
                else          Cf[(size_t)(row0 + r) * N + col] = val;
            }
        }
    }
}

// ---------- per-token cross-head attention ----------
// qkv: [N, 3072] bf16 (q | k | v), out: [N, 1024] bf16
// one thread per (token, head): 16x16 scores, softmax over key-heads, 16x64 PV
__global__ __launch_bounds__(256) void attn_k(const short* __restrict__ qkv,
                                              short* __restrict__ out) {
    int gid = blockIdx.x * 256 + threadIdx.x;
    int t = gid >> 4, h = gid & 15;
    const short* q  = qkv + (size_t)t * 3072 + h * 64;
    const short* kb = qkv + (size_t)t * 3072 + 1024;
    const short* vb = qkv + (size_t)t * 3072 + 2048;

    float qf[64];
#pragma unroll
    for (int j = 0; j < 8; ++j) {
        short8 qv = *(const short8*)(q + j * 8);
#pragma unroll
        for (int i = 0; i < 8; ++i) qf[j * 8 + i] = b2f(qv[i]);
    }

    float s[16];
    float mx = -1e30f;
#pragma unroll
    for (int g = 0; g < 16; ++g) {
        float a = 0.f;
#pragma unroll
        for (int j = 0; j < 8; ++j) {
            short8 kv = *(const short8*)(kb + g * 64 + j * 8);
#pragma unroll
            for (int i = 0; i < 8; ++i) a += qf[j * 8 + i] * b2f(kv[i]);
        }
        s[g] = a * 0.125f;   // scale = 1/sqrt(64)
        mx = fmaxf(mx, s[g]);
    }
    float den = 0.f;
#pragma unroll
    for (int g = 0; g < 16; ++g) { s[g] = __expf(s[g] - mx); den += s[g]; }
    float inv = 1.f / den;

#pragma unroll
    for (int j = 0; j < 8; ++j) {
        float o[8] = {0.f, 0.f, 0.f, 0.f, 0.f, 0.f, 0.f, 0.f};
#pragma unroll
        for (int g = 0; g < 16; ++g) {
            short8 vv = *(const short8*)(vb + g * 64 + j * 8);
            float w = s[g];
#pragma unroll
            for (int i = 0; i < 8; ++i) o[i] += w * b2f(vv[i]);
        }
        short8 ov;
#pragma unroll
        for (int i = 0; i < 8; ++i) ov[i] = (short)f2b(o[i] * inv);
        *(short8*)(out + (size_t)t * 1024 + h * 64 + j * 8) = ov;
    }
}

// ---------- launch ----------
extern "C" void kernel_launch(void* const* d_in, const int* in_sizes, int n_in,
                              void* d_out, int out_size, void* d_ws, size_t ws_size,
                              hipStream_t stream) {
    const float* x  = (const float*)d_in[0];
    const float* Wq = (const float*)d_in[1];
    const float* bq = (const float*)d_in[2];
    const float* Wk = (const float*)d_in[3];
    const float* bk = (const float*)d_in[4];
    const float* Wv = (const float*)d_in[5];
    const float* bv = (const float*)d_in[6];
    const float* Wo = (const float*)d_in[7];
    const float* bo = (const float*)d_in[8];
    float* out = (float*)d_out;

    const int N = 32768, E = 1024;

    char* ws = (char*)d_ws;
    size_t off = 0;
    short* xb = (short*)(ws + off);         off += (size_t)N * E * 2;          // 64 MiB
    short* wqkv = (short*)(ws + off);       off += (size_t)3 * E * E * 2;      // 6 MiB
    short* wo = (short*)(ws + off);         off += (size_t)E * E * 2;          // 2 MiB
    float* bqkv = (float*)(ws + off);       off += (size_t)3 * E * 4;          // 12 KiB
    off = (off + 255) & ~(size_t)255;
    short* y1 = (short*)(ws + off);         off += (size_t)N * 3 * E * 2;      // 192 MiB
    short* ao = xb;  // reuse xb region: dead after GEMM1, attn writes here

    // 1) convert x and weights to bf16
    cvt_bf16<<<dim3((N * E / 8 + 255) / 256), dim3(256), 0, stream>>>(x, (unsigned short*)xb, N * E / 8);
    cvt_bf16<<<dim3((E * E / 8 + 255) / 256), dim3(256), 0, stream>>>(Wq, (unsigned short*)wqkv, E * E / 8);
    cvt_bf16<<<dim3((E * E / 8 + 255) / 256), dim3(256), 0, stream>>>(Wk, (unsigned short*)(wqkv + (size_t)E * E), E * E / 8);
    cvt_bf16<<<dim3((E * E / 8 + 255) / 256), dim3(256), 0, stream>>>(Wv, (unsigned short*)(wqkv + (size_t)2 * E * E), E * E / 8);
    cvt_bf16<<<dim3((E * E / 8 + 255) / 256), dim3(256), 0, stream>>>(Wo, (unsigned short*)wo, E * E / 8);
    concat3<<<dim3(12), dim3(256), 0, stream>>>(bq, bk, bv, bqkv);

    // 2) fused QKV projection: y1[N, 3072] = xb @ wqkv^T + bqkv  (bf16 out)
    //    grid = (32768/256)*(3072/128) = 128*24 = 3072 blocks (%8==0)
    gemm_bt<true><<<dim3((N / 256) * (3 * E / 128)), dim3(512), 0, stream>>>(
        xb, wqkv, bqkv, (unsigned short*)y1, nullptr, N, 3 * E, E);

    // 3) per-token attention: ao[N, 1024] bf16
    attn_k<<<dim3(N * 16 / 256), dim3(256), 0, stream>>>(y1, ao);

    // 4) output projection: out[N, 1024] = ao @ wo^T + bo  (fp32 out)
    //    grid = 128*8 = 1024 blocks (%8==0)
    gemm_bt<false><<<dim3((N / 256) * (E / 128)), dim3(512), 0, stream>>>(
        ao, wo, bo, nullptr, out, N, E, E);
}

// Round 3
// 484.003 us; speedup vs baseline: 1.2105x; 1.0395x over previous
//
#include <hip/hip_runtime.h>

// ---------- types ----------
typedef __attribute__((ext_vector_type(8))) short short8;
typedef __attribute__((ext_vector_type(8))) unsigned short ushort8;
typedef __attribute__((ext_vector_type(4))) float f32x4;

__device__ __forceinline__ float b2f(short s) {
    unsigned u = ((unsigned)(unsigned short)s) << 16;
    return __builtin_bit_cast(float, u);
}
__device__ __forceinline__ unsigned short f2b(float f) {
    unsigned u = __builtin_bit_cast(unsigned, f);
    u += 0x7fffu + ((u >> 16) & 1u);   // round-to-nearest-even
    return (unsigned short)(u >> 16);
}

// global -> LDS async copy, 16B per lane (wave-uniform LDS base + lane*16)
__device__ __forceinline__ void gload_lds16(const void* gptr, void* ldsptr) {
    typedef __attribute__((address_space(1))) const void gv_t;
    typedef __attribute__((address_space(3))) void lv_t;
    gv_t* g = reinterpret_cast<gv_t*>(reinterpret_cast<unsigned long long>(gptr));
    lv_t* l = reinterpret_cast<lv_t*>((unsigned int)reinterpret_cast<unsigned long long>(ldsptr));
    __builtin_amdgcn_global_load_lds(g, l, 16, 0, 0);
}

#define MEMFENCE() asm volatile("" ::: "memory")
#define BARRIER() do { MEMFENCE(); __builtin_amdgcn_s_barrier(); MEMFENCE(); } while (0)
// rule #18: sched_barrier(0) after inline-asm lgkmcnt so MFMA can't hoist past it
#define LGKM0() do { asm volatile("s_waitcnt lgkmcnt(0)" ::: "memory"); __builtin_amdgcn_sched_barrier(0); } while (0)
#define LGKM8() do { asm volatile("s_waitcnt lgkmcnt(8)" ::: "memory"); __builtin_amdgcn_sched_barrier(0); } while (0)

// ---------- fp32 -> bf16 conversion (8 elems/thread) ----------
__global__ __launch_bounds__(256) void cvt_bf16(const float* __restrict__ in,
                                                unsigned short* __restrict__ out,
                                                int n8) {
    int i = blockIdx.x * 256 + threadIdx.x;
    if (i >= n8) return;
    const float4* p = (const float4*)in + (size_t)i * 2;
    float4 a = p[0], b = p[1];
    ushort8 o;
    o[0] = f2b(a.x); o[1] = f2b(a.y); o[2] = f2b(a.z); o[3] = f2b(a.w);
    o[4] = f2b(b.x); o[5] = f2b(b.y); o[6] = f2b(b.z); o[7] = f2b(b.w);
    *(ushort8*)(out + (size_t)i * 8) = o;
}

// ---------- concat 3 bias vectors (each 1024) ----------
__global__ __launch_bounds__(256) void concat3(const float* __restrict__ a,
                                               const float* __restrict__ b,
                                               const float* __restrict__ c,
                                               float* __restrict__ o) {
    int i = blockIdx.x * 256 + threadIdx.x;  // 0..3071
    float v = (i < 1024) ? a[i] : (i < 2048 ? b[i - 1024] : c[i - 2048]);
    o[i] = v;
}

// ---------- bf16 GEMM, C[m,n] = sum_k A[m,k]*B[n,k] + bias[n] ----------
// 256x256 tile, BK=64, 512 threads (8 waves, 2x4), per-wave out 128x64.
// LDS 128 KiB: 2 dbuf x 2 halves x [128][64] per operand. 4 phases per K-tile:
//   phase = { stage 1 half-tile (2 gload_lds) | ds_read frag subtile |
//             lgkmcnt -> setprio(1) 16 MFMA setprio(0) -> s_barrier }
// Half-tile stream: at tile T phase q, stage s = 4T+q-3 -> tile (s>>2)+2,
// half s&3 (0:A.h0 1:A.h1 2:B.h0 3:B.h1). Counted vmcnt(2) once per tile
// (tile T+1 fully landed; only this-phase's 2 loads left in flight).
// Hazard proof: A-frag reads complete at q2's lgkmcnt(0), B per-phase with
// lgkmcnt(0) before each phase's closing barrier -> every overwrite stage is
// issued >=1 barrier after the victim's formal read completion.
template <bool OUT_BF16>
__global__ __launch_bounds__(512, 2) void gemm_bt(const short* __restrict__ A,   // [M,K] bf16
                                                  const short* __restrict__ B,   // [N,K] bf16
                                                  const float* __restrict__ bias,// [N]
                                                  unsigned short* __restrict__ Cb,
                                                  float* __restrict__ Cf,
                                                  int M, int N, int K) {
    extern __shared__ short lds[];
    short* Ab = lds;                       // [2][2][128][64]
    short* Bb = lds + 2 * 2 * 128 * 64;    // [2][2][128][64]

    const int lane = threadIdx.x & 63;
    const int wave = threadIdx.x >> 6;
    const int wr = wave >> 2;      // 0..1: wave row (128 rows)
    const int wc = wave & 3;       // 0..3: wave col (64 cols)

    // XCD-aware swizzle (grid % 8 == 0 for both calls)
    const int nwg = gridDim.x;
    const int bid = blockIdx.x;
    const int swz = (bid & 7) * (nwg >> 3) + (bid >> 3);
    const int ncol = N >> 8;
    const int trow = swz / ncol, tcol = swz % ncol;

    const short* Ablk = A + (size_t)trow * 256 * K;
    const short* Bblk = B + (size_t)tcol * 256 * K;

    // staging: wave covers 8-row stripes; source col pre-swizzled (granule ^= row&7)
    const int scol_sw = ((lane & 7) ^ (lane >> 3)) * 8;
    const int rl = lane & 15;
    const int g0 = (((lane >> 4)) ^ (lane & 7)) * 8;       // ks0 granule (shorts)
    const int g1 = ((4 + (lane >> 4)) ^ (lane & 7)) * 8;   // ks1 granule

    short8 af[8][2];
    short8 bf[4];
    f32x4 acc[8][4] = {};

    const int NT = K >> 6;
    const int smax = 4 * (NT - 2);

    auto stage_half = [&](int ts, int h) {
        const int dd = ts & 1;
        const int hh = h & 1;
        const short* gb = ((h < 2) ? Ablk : Bblk) + (size_t)(hh * 128) * K + (ts << 6) + scol_sw;
        short* lb = ((h < 2) ? Ab : Bb) + (((dd << 1) | hh) << 13);
#pragma unroll
        for (int c = 0; c < 2; ++c) {
            const int row = c * 64 + wave * 8 + (lane >> 3);
            gload_lds16(gb + (size_t)row * K, lb + ((c * 64 + wave * 8) << 6));
        }
    };
    auto stage_if = [&](int s) { if (s >= 0 && s < smax) stage_half((s >> 2) + 2, s & 3); };

    auto readA = [&](int d, int ks) {
        const short* base = Ab + ((((d << 1) | wr) << 13)) + (ks ? g1 : g0);
#pragma unroll
        for (int m = 0; m < 8; ++m)
            af[m][ks] = *(const short8*)(base + ((m * 16 + rl) << 6));
    };
    auto readB = [&](int d, int ks, int np) {
        const short* base = Bb + ((((d << 1) | (wc >> 1)) << 13)) + (((wc & 1) * 64) << 6) + (ks ? g1 : g0);
#pragma unroll
        for (int j = 0; j < 2; ++j)
            bf[np * 2 + j] = *(const short8*)(base + (((np * 2 + j) * 16 + rl) << 6));
    };
    auto mmq = [&](int ks, int np) {
        __builtin_amdgcn_s_setprio(1);
#pragma unroll
        for (int m = 0; m < 8; ++m) {
            acc[m][np * 2]     = __builtin_amdgcn_mfma_f32_16x16x32_bf16(af[m][ks], bf[np * 2],     acc[m][np * 2], 0, 0, 0);
            acc[m][np * 2 + 1] = __builtin_amdgcn_mfma_f32_16x16x32_bf16(af[m][ks], bf[np * 2 + 1], acc[m][np * 2 + 1], 0, 0, 0);
        }
        __builtin_amdgcn_s_setprio(0);
    };

    // prologue: tiles 0,1 fully staged (16 gloads/thread); wait tile0, keep tile1 in flight
#pragma unroll
    for (int t = 0; t < 2; ++t)
#pragma unroll
        for (int h = 0; h < 4; ++h) stage_half(t, h);
    asm volatile("s_waitcnt vmcnt(8)" ::: "memory");
    BARRIER();

#pragma unroll 2
    for (int T = 0; T < NT; ++T) {
        const int d = T & 1;
        const int s0 = 4 * T;
        // phase 0: A[ks0] + B[01][ks0]
        stage_if(s0 - 3);
        readA(d, 0); readB(d, 0, 0);
        LGKM0();
        mmq(0, 0);
        BARRIER();
        // phase 1: B[23][ks0] + A[ks1] (B issued first; LGKM8 leaves A in flight)
        stage_if(s0 - 2);
        readB(d, 0, 1); readA(d, 1);
        LGKM8();
        mmq(0, 1);
        BARRIER();
        // phase 2: B[01][ks1]
        stage_if(s0 - 1);
        readB(d, 1, 0);
        LGKM0();
        mmq(1, 0);
        BARRIER();
        // phase 3: B[23][ks1]; per-tile counted vmcnt before closing barrier
        stage_if(s0);
        readB(d, 1, 1);
        LGKM0();
        mmq(1, 1);
        if (T < NT - 2)       asm volatile("s_waitcnt vmcnt(2)" ::: "memory");
        else if (T == NT - 2) asm volatile("s_waitcnt vmcnt(0)" ::: "memory");
        BARRIER();
    }

    // epilogue: C/D layout col = lane&15, row = (lane>>4)*4 + r
    const int crow0 = trow * 256 + wr * 128 + (lane >> 4) * 4;
    const int ccol0 = tcol * 256 + wc * 64 + rl;
#pragma unroll
    for (int n = 0; n < 4; ++n) {
        const int col = ccol0 + n * 16;
        const float bv = bias[col];
#pragma unroll
        for (int m = 0; m < 8; ++m) {
            const int row0 = crow0 + m * 16;
#pragma unroll
            for (int r = 0; r < 4; ++r) {
                float val = acc[m][n][r] + bv;
                if (OUT_BF16) Cb[(size_t)(row0 + r) * N + col] = f2b(val);
                else          Cf[(size_t)(row0 + r) * N + col] = val;
            }
        }
    }
}

// ---------- per-token cross-head attention ----------
// qkv: [N, 3072] bf16 (q | k | v), out: [N, 1024] bf16
// one thread per (token, head): 16x16 scores, softmax over key-heads, 16x64 PV
__global__ __launch_bounds__(256) void attn_k(const short* __restrict__ qkv,
                                              short* __restrict__ out) {
    int gid = blockIdx.x * 256 + threadIdx.x;
    int t = gid >> 4, h = gid & 15;
    const short* q  = qkv + (size_t)t * 3072 + h * 64;
    const short* kb = qkv + (size_t)t * 3072 + 1024;
    const short* vb = qkv + (size_t)t * 3072 + 2048;

    float qf[64];
#pragma unroll
    for (int j = 0; j < 8; ++j) {
        short8 qv = *(const short8*)(q + j * 8);
#pragma unroll
        for (int i = 0; i < 8; ++i) qf[j * 8 + i] = b2f(qv[i]);
    }

    float s[16];
    float mx = -1e30f;
#pragma unroll
    for (int g = 0; g < 16; ++g) {
        float a = 0.f;
#pragma unroll
        for (int j = 0; j < 8; ++j) {
            short8 kv = *(const short8*)(kb + g * 64 + j * 8);
#pragma unroll
            for (int i = 0; i < 8; ++i) a += qf[j * 8 + i] * b2f(kv[i]);
        }
        s[g] = a * 0.125f;   // scale = 1/sqrt(64)
        mx = fmaxf(mx, s[g]);
    }
    float den = 0.f;
#pragma unroll
    for (int g = 0; g < 16; ++g) { s[g] = __expf(s[g] - mx); den += s[g]; }
    float inv = 1.f / den;

#pragma unroll
    for (int j = 0; j < 8; ++j) {
        float o[8] = {0.f, 0.f, 0.f, 0.f, 0.f, 0.f, 0.f, 0.f};
#pragma unroll
        for (int g = 0; g < 16; ++g) {
            short8 vv = *(const short8*)(vb + g * 64 + j * 8);
            float w = s[g];
#pragma unroll
            for (int i = 0; i < 8; ++i) o[i] += w * b2f(vv[i]);
        }
        short8 ov;
#pragma unroll
        for (int i = 0; i < 8; ++i) ov[i] = (short)f2b(o[i] * inv);
        *(short8*)(out + (size_t)t * 1024 + h * 64 + j * 8) = ov;
    }
}

// ---------- launch ----------
extern "C" void kernel_launch(void* const* d_in, const int* in_sizes, int n_in,
                              void* d_out, int out_size, void* d_ws, size_t ws_size,
                              hipStream_t stream) {
    const float* x  = (const float*)d_in[0];
    const float* Wq = (const float*)d_in[1];
    const float* bq = (const float*)d_in[2];
    const float* Wk = (const float*)d_in[3];
    const float* bk = (const float*)d_in[4];
    const float* Wv = (const float*)d_in[5];
    const float* bv = (const float*)d_in[6];
    const float* Wo = (const float*)d_in[7];
    const float* bo = (const float*)d_in[8];
    float* out = (float*)d_out;

    const int N = 32768, E = 1024;
    const int LDS_BYTES = 131072;

    (void)hipFuncSetAttribute((const void*)gemm_bt<true>,  hipFuncAttributeMaxDynamicSharedMemorySize, LDS_BYTES);
    (void)hipFuncSetAttribute((const void*)gemm_bt<false>, hipFuncAttributeMaxDynamicSharedMemorySize, LDS_BYTES);

    char* ws = (char*)d_ws;
    size_t off = 0;
    short* xb = (short*)(ws + off);         off += (size_t)N * E * 2;          // 64 MiB
    short* wqkv = (short*)(ws + off);       off += (size_t)3 * E * E * 2;      // 6 MiB
    short* wo = (short*)(ws + off);         off += (size_t)E * E * 2;          // 2 MiB
    float* bqkv = (float*)(ws + off);       off += (size_t)3 * E * 4;          // 12 KiB
    off = (off + 255) & ~(size_t)255;
    short* y1 = (short*)(ws + off);         off += (size_t)N * 3 * E * 2;      // 192 MiB
    short* ao = xb;  // reuse xb region: dead after GEMM1, attn writes here

    // 1) convert x and weights to bf16
    cvt_bf16<<<dim3((N * E / 8 + 255) / 256), dim3(256), 0, stream>>>(x, (unsigned short*)xb, N * E / 8);
    cvt_bf16<<<dim3((E * E / 8 + 255) / 256), dim3(256), 0, stream>>>(Wq, (unsigned short*)wqkv, E * E / 8);
    cvt_bf16<<<dim3((E * E / 8 + 255) / 256), dim3(256), 0, stream>>>(Wk, (unsigned short*)(wqkv + (size_t)E * E), E * E / 8);
    cvt_bf16<<<dim3((E * E / 8 + 255) / 256), dim3(256), 0, stream>>>(Wv, (unsigned short*)(wqkv + (size_t)2 * E * E), E * E / 8);
    cvt_bf16<<<dim3((E * E / 8 + 255) / 256), dim3(256), 0, stream>>>(Wo, (unsigned short*)wo, E * E / 8);
    concat3<<<dim3(12), dim3(256), 0, stream>>>(bq, bk, bv, bqkv);

    // 2) fused QKV projection: y1[N, 3072] = xb @ wqkv^T + bqkv  (bf16 out)
    //    grid = (32768/256)*(3072/256) = 128*12 = 1536 blocks (%8==0)
    gemm_bt<true><<<dim3((N / 256) * (3 * E / 256)), dim3(512), LDS_BYTES, stream>>>(
        xb, wqkv, bqkv, (unsigned short*)y1, nullptr, N, 3 * E, E);

    // 3) per-token attention: ao[N, 1024] bf16
    attn_k<<<dim3(N * 16 / 256), dim3(256), 0, stream>>>(y1, ao);

    // 4) output projection: out[N, 1024] = ao @ wo^T + bo  (fp32 out)
    //    grid = 128*4 = 512 blocks (%8==0)
    gemm_bt<false><<<dim3((N / 256) * (E / 256)), dim3(512), LDS_BYTES, stream>>>(
        ao, wo, bo, nullptr, out, N, E, E);
}

// Round 4
// 478.031 us; speedup vs baseline: 1.2256x; 1.0125x over previous
//
#include <hip/hip_runtime.h>

// ---------- types ----------
typedef __attribute__((ext_vector_type(8))) short short8;
typedef __attribute__((ext_vector_type(8))) unsigned short ushort8;
typedef __attribute__((ext_vector_type(4))) float f32x4;

__device__ __forceinline__ float b2f(short s) {
    unsigned u = ((unsigned)(unsigned short)s) << 16;
    return __builtin_bit_cast(float, u);
}
__device__ __forceinline__ unsigned short f2b(float f) {
    unsigned u = __builtin_bit_cast(unsigned, f);
    u += 0x7fffu + ((u >> 16) & 1u);   // round-to-nearest-even
    return (unsigned short)(u >> 16);
}

// global -> LDS async copy, 16B per lane (wave-uniform LDS base + lane*16)
__device__ __forceinline__ void gload_lds16(const void* gptr, void* ldsptr) {
    typedef __attribute__((address_space(1))) const void gv_t;
    typedef __attribute__((address_space(3))) void lv_t;
    gv_t* g = reinterpret_cast<gv_t*>(reinterpret_cast<unsigned long long>(gptr));
    lv_t* l = reinterpret_cast<lv_t*>((unsigned int)reinterpret_cast<unsigned long long>(ldsptr));
    __builtin_amdgcn_global_load_lds(g, l, 16, 0, 0);
}

#define MEMFENCE() asm volatile("" ::: "memory")
#define BARRIER() do { MEMFENCE(); __builtin_amdgcn_s_barrier(); MEMFENCE(); } while (0)

// ---------- fp32 -> bf16 conversion (8 elems/thread) ----------
__global__ __launch_bounds__(256) void cvt_bf16(const float* __restrict__ in,
                                                unsigned short* __restrict__ out,
                                                int n8) {
    int i = blockIdx.x * 256 + threadIdx.x;
    if (i >= n8) return;
    const float4* p = (const float4*)in + (size_t)i * 2;
    float4 a = p[0], b = p[1];
    ushort8 o;
    o[0] = f2b(a.x); o[1] = f2b(a.y); o[2] = f2b(a.z); o[3] = f2b(a.w);
    o[4] = f2b(b.x); o[5] = f2b(b.y); o[6] = f2b(b.z); o[7] = f2b(b.w);
    *(ushort8*)(out + (size_t)i * 8) = o;
}

// ---------- concat 3 bias vectors (each 1024) ----------
__global__ __launch_bounds__(256) void concat3(const float* __restrict__ a,
                                               const float* __restrict__ b,
                                               const float* __restrict__ c,
                                               float* __restrict__ o) {
    int i = blockIdx.x * 256 + threadIdx.x;  // 0..3071
    float v = (i < 1024) ? a[i] : (i < 2048 ? b[i - 1024] : c[i - 2048]);
    o[i] = v;
}

// ---------- bf16 GEMM, C[m,n] = sum_k A[m,k]*B[n,k] + bias[n] ----------
// 256x256 tile, BK=64, 512 threads (8 waves, 2x4), per-wave out 128x64.
// LDS 128 KiB: [2 dbuf][2 half][128][64] per operand.
// m201-faithful 4-phase skeleton per K-tile (quadrant (mh,nh) per phase):
//   { ds_reads issue; stage 1 half (2 gloads); (lgkm8 if 12 reads);
//     s_barrier; lgkmcnt(0); setprio(1) 16 MFMA setprio(0); s_barrier }
// Reads queued BEFORE the open barrier -> their retirement staggers across
// the LDS pipe while early waves MFMA (T5's role-split). No sched_barrier(0)
// anywhere (m141 order-pinning regression); C++ ds_reads carry compiler-exact
// dependency waits, the asm lgkmcnt is only the template's hint.
// Half-tile stream: at tile T phase q, stage s=4T+q-3 -> tile (s>>2)+2,
// half s&3 (0:A.h0 1:A.h1 2:B.h0 3:B.h1). vmcnt(2) once per tile before p3's
// closing barrier publishes tile T+1. Closing barriers order every stage
// after all waves' formal read drains (overwrite-hazard proof as R3).
template <bool OUT_BF16>
__global__ __launch_bounds__(512, 2) void gemm_bt(const short* __restrict__ A,   // [M,K] bf16
                                                  const short* __restrict__ B,   // [N,K] bf16
                                                  const float* __restrict__ bias,// [N]
                                                  unsigned short* __restrict__ Cb,
                                                  float* __restrict__ Cf,
                                                  int M, int N, int K) {
    extern __shared__ short lds[];
    short* Ab = lds;                       // [2][2][128][64]
    short* Bb = lds + 2 * 2 * 128 * 64;    // [2][2][128][64]

    const int lane = threadIdx.x & 63;
    const int wave = threadIdx.x >> 6;
    const int wr = wave >> 2;      // 0..1: wave row (128 rows)
    const int wc = wave & 3;       // 0..3: wave col (64 cols)

    // XCD-aware swizzle (grid % 8 == 0 for both calls)
    const int nwg = gridDim.x;
    const int bid = blockIdx.x;
    const int swz = (bid & 7) * (nwg >> 3) + (bid >> 3);
    const int ncol = N >> 8;
    const int trow = swz / ncol, tcol = swz % ncol;

    const short* Ablk = A + (size_t)trow * 256 * K;
    const short* Bblk = B + (size_t)tcol * 256 * K;

    // staging: wave covers 8-row stripes; source col pre-swizzled (granule ^= row&7)
    const int scol_sw = ((lane & 7) ^ (lane >> 3)) * 8;
    const int rl = lane & 15;
    const int g0 = (((lane >> 4)) ^ (lane & 7)) * 8;       // ks0 granule (shorts)
    const int g1 = ((4 + (lane >> 4)) ^ (lane & 7)) * 8;   // ks1 granule

    short8 af[4][2];   // current mh-quadrant A frags (4 m x 2 ks)
    short8 bf[4][2];   // both nh B frags (4 n x 2 ks)
    f32x4 acc[8][4] = {};

    const int NT = K >> 6;
    const int smax = 4 * (NT - 2);

    auto stage_half = [&](int ts, int h) {
        const int dd = ts & 1;
        const int hh = h & 1;
        const short* gb = ((h < 2) ? Ablk : Bblk) + (size_t)(hh * 128) * K + (ts << 6) + scol_sw;
        short* lb = ((h < 2) ? Ab : Bb) + (((dd << 1) | hh) << 13);
#pragma unroll
        for (int c = 0; c < 2; ++c) {
            const int row = c * 64 + wave * 8 + (lane >> 3);
            gload_lds16(gb + (size_t)row * K, lb + ((c * 64 + wave * 8) << 6));
        }
    };
    auto stage_if = [&](int s) { if (s >= 0 && s < smax) stage_half((s >> 2) + 2, s & 3); };

    auto readA = [&](int d, int mh) {
        const short* base = Ab + (((d << 1) | wr) << 13) + ((mh * 64 + rl) << 6);
#pragma unroll
        for (int m = 0; m < 4; ++m) {
            af[m][0] = *(const short8*)(base + ((m * 16) << 6) + g0);
            af[m][1] = *(const short8*)(base + ((m * 16) << 6) + g1);
        }
    };
    auto readB = [&](int d, int nh) {
        const short* base = Bb + (((d << 1) | (wc >> 1)) << 13) + (((wc & 1) * 64 + rl) << 6);
#pragma unroll
        for (int j = 0; j < 2; ++j) {
            bf[nh * 2 + j][0] = *(const short8*)(base + (((nh * 2 + j) * 16) << 6) + g0);
            bf[nh * 2 + j][1] = *(const short8*)(base + (((nh * 2 + j) * 16) << 6) + g1);
        }
    };
    auto mm = [&](int mh, int nh) {
        __builtin_amdgcn_s_setprio(1);
#pragma unroll
        for (int ks = 0; ks < 2; ++ks)
#pragma unroll
            for (int m = 0; m < 4; ++m)
#pragma unroll
                for (int j = 0; j < 2; ++j)
                    acc[mh * 4 + m][nh * 2 + j] = __builtin_amdgcn_mfma_f32_16x16x32_bf16(
                        af[m][ks], bf[nh * 2 + j][ks], acc[mh * 4 + m][nh * 2 + j], 0, 0, 0);
        __builtin_amdgcn_s_setprio(0);
    };

    auto tile_body = [&](int T, int d) {
        const int s0 = 4 * T;
        // p0: quadrant (0,0); reads A[mh0](8) + B[nh0](4) = 12
        readA(d, 0); readB(d, 0);
        stage_if(s0 - 3);
        asm volatile("s_waitcnt lgkmcnt(8)" ::: "memory");
        BARRIER();
        asm volatile("s_waitcnt lgkmcnt(0)" ::: "memory");
        mm(0, 0);
        BARRIER();
        // p1: quadrant (0,1); reads B[nh1](4)
        readB(d, 1);
        stage_if(s0 - 2);
        BARRIER();
        asm volatile("s_waitcnt lgkmcnt(0)" ::: "memory");
        mm(0, 1);
        BARRIER();
        // p2: quadrant (1,0); reads A[mh1](8)
        readA(d, 1);
        stage_if(s0 - 1);
        BARRIER();
        asm volatile("s_waitcnt lgkmcnt(0)" ::: "memory");
        mm(1, 0);
        BARRIER();
        // p3: quadrant (1,1); 0 reads; per-tile counted vmcnt then publish barrier
        stage_if(s0);
        BARRIER();
        mm(1, 1);
        if (T < NT - 2)       asm volatile("s_waitcnt vmcnt(2)" ::: "memory");
        else if (T == NT - 2) asm volatile("s_waitcnt vmcnt(0)" ::: "memory");
        BARRIER();
    };

    // prologue: tiles 0,1 fully staged; wait tile0 landed, keep tile1 in flight
#pragma unroll
    for (int t = 0; t < 2; ++t)
#pragma unroll
        for (int h = 0; h < 4; ++h) stage_half(t, h);
    asm volatile("s_waitcnt vmcnt(8)" ::: "memory");
    BARRIER();

    for (int T2 = 0; T2 < NT; T2 += 2) {   // NT even (K % 128 == 0)
        tile_body(T2, 0);
        tile_body(T2 + 1, 1);
    }

    // epilogue: C/D layout col = lane&15, row = (lane>>4)*4 + r
    const int crow0 = trow * 256 + wr * 128 + (lane >> 4) * 4;
    const int ccol0 = tcol * 256 + wc * 64 + rl;
#pragma unroll
    for (int n = 0; n < 4; ++n) {
        const int col = ccol0 + n * 16;
        const float bv = bias[col];
#pragma unroll
        for (int m = 0; m < 8; ++m) {
            const int row0 = crow0 + m * 16;
#pragma unroll
            for (int r = 0; r < 4; ++r) {
                float val = acc[m][n][r] + bv;
                if (OUT_BF16) Cb[(size_t)(row0 + r) * N + col] = f2b(val);
                else          Cf[(size_t)(row0 + r) * N + col] = val;
            }
        }
    }
}

// ---------- per-token cross-head attention ----------
// qkv: [N, 3072] bf16 (q | k | v), out: [N, 1024] bf16
// one thread per (token, head): 16x16 scores, softmax over key-heads, 16x64 PV
__global__ __launch_bounds__(256) void attn_k(const short* __restrict__ qkv,
                                              short* __restrict__ out) {
    int gid = blockIdx.x * 256 + threadIdx.x;
    int t = gid >> 4, h = gid & 15;
    const short* q  = qkv + (size_t)t * 3072 + h * 64;
    const short* kb = qkv + (size_t)t * 3072 + 1024;
    const short* vb = qkv + (size_t)t * 3072 + 2048;

    float qf[64];
#pragma unroll
    for (int j = 0; j < 8; ++j) {
        short8 qv = *(const short8*)(q + j * 8);
#pragma unroll
        for (int i = 0; i < 8; ++i) qf[j * 8 + i] = b2f(qv[i]);
    }

    float s[16];
    float mx = -1e30f;
#pragma unroll
    for (int g = 0; g < 16; ++g) {
        float a = 0.f;
#pragma unroll
        for (int j = 0; j < 8; ++j) {
            short8 kv = *(const short8*)(kb + g * 64 + j * 8);
#pragma unroll
            for (int i = 0; i < 8; ++i) a += qf[j * 8 + i] * b2f(kv[i]);
        }
        s[g] = a * 0.125f;   // scale = 1/sqrt(64)
        mx = fmaxf(mx, s[g]);
    }
    float den = 0.f;
#pragma unroll
    for (int g = 0; g < 16; ++g) { s[g] = __expf(s[g] - mx); den += s[g]; }
    float inv = 1.f / den;

#pragma unroll
    for (int j = 0; j < 8; ++j) {
        float o[8] = {0.f, 0.f, 0.f, 0.f, 0.f, 0.f, 0.f, 0.f};
#pragma unroll
        for (int g = 0; g < 16; ++g) {
            short8 vv = *(const short8*)(vb + g * 64 + j * 8);
            float w = s[g];
#pragma unroll
            for (int i = 0; i < 8; ++i) o[i] += w * b2f(vv[i]);
        }
        short8 ov;
#pragma unroll
        for (int i = 0; i < 8; ++i) ov[i] = (short)f2b(o[i] * inv);
        *(short8*)(out + (size_t)t * 1024 + h * 64 + j * 8) = ov;
    }
}

// ---------- launch ----------
extern "C" void kernel_launch(void* const* d_in, const int* in_sizes, int n_in,
                              void* d_out, int out_size, void* d_ws, size_t ws_size,
                              hipStream_t stream) {
    const float* x  = (const float*)d_in[0];
    const float* Wq = (const float*)d_in[1];
    const float* bq = (const float*)d_in[2];
    const float* Wk = (const float*)d_in[3];
    const float* bk = (const float*)d_in[4];
    const float* Wv = (const float*)d_in[5];
    const float* bv = (const float*)d_in[6];
    const float* Wo = (const float*)d_in[7];
    const float* bo = (const float*)d_in[8];
    float* out = (float*)d_out;

    const int N = 32768, E = 1024;
    const int LDS_BYTES = 131072;

    (void)hipFuncSetAttribute((const void*)gemm_bt<true>,  hipFuncAttributeMaxDynamicSharedMemorySize, LDS_BYTES);
    (void)hipFuncSetAttribute((const void*)gemm_bt<false>, hipFuncAttributeMaxDynamicSharedMemorySize, LDS_BYTES);

    char* ws = (char*)d_ws;
    size_t off = 0;
    short* xb = (short*)(ws + off);         off += (size_t)N * E * 2;          // 64 MiB
    short* wqkv = (short*)(ws + off);       off += (size_t)3 * E * E * 2;      // 6 MiB
    short* wo = (short*)(ws + off);         off += (size_t)E * E * 2;          // 2 MiB
    float* bqkv = (float*)(ws + off);       off += (size_t)3 * E * 4;          // 12 KiB
    off = (off + 255) & ~(size_t)255;
    short* y1 = (short*)(ws + off);         off += (size_t)N * 3 * E * 2;      // 192 MiB
    short* ao = xb;  // reuse xb region: dead after GEMM1, attn writes here

    // 1) convert x and weights to bf16
    cvt_bf16<<<dim3((N * E / 8 + 255) / 256), dim3(256), 0, stream>>>(x, (unsigned short*)xb, N * E / 8);
    cvt_bf16<<<dim3((E * E / 8 + 255) / 256), dim3(256), 0, stream>>>(Wq, (unsigned short*)wqkv, E * E / 8);
    cvt_bf16<<<dim3((E * E / 8 + 255) / 256), dim3(256), 0, stream>>>(Wk, (unsigned short*)(wqkv + (size_t)E * E), E * E / 8);
    cvt_bf16<<<dim3((E * E / 8 + 255) / 256), dim3(256), 0, stream>>>(Wv, (unsigned short*)(wqkv + (size_t)2 * E * E), E * E / 8);
    cvt_bf16<<<dim3((E * E / 8 + 255) / 256), dim3(256), 0, stream>>>(Wo, (unsigned short*)wo, E * E / 8);
    concat3<<<dim3(12), dim3(256), 0, stream>>>(bq, bk, bv, bqkv);

    // 2) fused QKV projection: y1[N, 3072] = xb @ wqkv^T + bqkv  (bf16 out)
    //    grid = (32768/256)*(3072/256) = 128*12 = 1536 blocks (%8==0)
    gemm_bt<true><<<dim3((N / 256) * (3 * E / 256)), dim3(512), LDS_BYTES, stream>>>(
        xb, wqkv, bqkv, (unsigned short*)y1, nullptr, N, 3 * E, E);

    // 3) per-token attention: ao[N, 1024] bf16
    attn_k<<<dim3(N * 16 / 256), dim3(256), 0, stream>>>(y1, ao);

    // 4) output projection: out[N, 1024] = ao @ wo^T + bo  (fp32 out)
    //    grid = 128*4 = 512 blocks (%8==0)
    gemm_bt<false><<<dim3((N / 256) * (E / 256)), dim3(512), LDS_BYTES, stream>>>(
        ao, wo, bo, nullptr, out, N, E, E);
}